// Round 11
// baseline (46.920 us; speedup 1.0000x reference)
//
#include <hip/hip_runtime.h>
#include <hip/hip_bf16.h>

#define SIG   1000
#define MROWS 8192
#define FK    512    // folded K (500 used, padded)
#define NPAD  1024   // GEMM N: group0 = even-bin (cos,sin) pairs, group1 = odd-bin
#define PSDK  512    // psd padded columns (500 used) -> head GEMM K
#define HN    192    // head GEMM padded N (141 used)
#define NOUT  141
#define NT    16     // K-tiles (512/32)

using f32x4  = __attribute__((ext_vector_type(4))) float;
using short8 = __attribute__((ext_vector_type(8))) short;

__device__ inline ushort f2bf(float f) {
  union { float f; unsigned u; } v; v.f = f;
  unsigned u = v.u;
  return (ushort)((u + 0x7FFFu + ((u >> 16) & 1u)) >> 16);   // RNE
}
__device__ inline uint pk2(float a, float b) {
  return (uint)f2bf(a) | ((uint)f2bf(b) << 16);
}
#define SB0() __builtin_amdgcn_sched_barrier(0)

// weights-only prep: rows [0,1024) -> Bt (on-device trig), [1024,1216) -> W3p
__global__ __launch_bounds__(256) void wprep_k(
    const float* __restrict__ W3, ushort* __restrict__ Bt,
    ushort* __restrict__ W3p) {
  const int row = blockIdx.x * 2 + (threadIdx.x >> 7);
  const int c   = threadIdx.x & 127;             // ushort4 chunk: k = 4c..4c+3
  if (row < NPAD) {
    const int cg = row & 511, g = row >> 9;
    ushort4 o = make_ushort4(0, 0, 0, 0);
    if (cg < 500) {
      const int m = 2 * (cg >> 1) + g;
      const int trig = cg & 1;
      const float C = 6.28318530717958647692f / 1000.0f;
      ushort v[4];
#pragma unroll
      for (int j = 0; j < 4; ++j) {
        int ph = ((4 * c + j) * m) % 1000;
        float ang = ph * C;
        v[j] = f2bf(trig ? __sinf(ang) : __cosf(ang));
      }
      o = make_ushort4(v[0], v[1], v[2], v[3]);
    }
    ((ushort4*)(Bt + (size_t)row * FK))[c] = o;
  } else {
    const int n = row - NPAD;
    ushort4 o = make_ushort4(0, 0, 0, 0);
    if (n < NOUT && c < 125) {
      const float4 w = *(const float4*)(W3 + (size_t)n * 500 + 4 * c);
      o.x = f2bf(w.x); o.y = f2bf(w.y); o.z = f2bf(w.z); o.w = f2bf(w.w);
    }
    ((ushort4*)(W3p + (size_t)n * PSDK))[c] = o;
  }
}

// Fused fold + DFT GEMM + psd epilogue. A is built on the fly from x:
// fh[r][k] = x[r][k]*filt[k] +/- x[r][k+500]*filt[k+500]  (sign by group).
// 128x128 tile, 512 thr / 8 waves (4x2 of 32x64), grid 512 (2 blk/CU).
// 3 LDS buffers; x reg-staged 1 iter ahead (fold overlaps MFMA); B via
// global_load_lds 2 ahead. Counted vmcnt ledger: top(6)/bottom(5), tail 1/0.
__global__ __launch_bounds__(512, 4) void gemm_psd_k(
    const float* __restrict__ x, const float* __restrict__ filt,
    const ushort* __restrict__ Bt, ushort* __restrict__ psd) {
  __shared__ ushort lA[3][128 * 32];   // 3 x 8 KiB
  __shared__ ushort lB[3][128 * 32];   // 3 x 8 KiB
  __shared__ float  fp[1024];          // fpA[0..511]=filt[k]|0, fpB=filt[k+500]|0
  const int tid  = threadIdx.x;
  const int wave = tid >> 6;
  const int lane = tid & 63;
  // bijective XCD swizzle: grid 512 = 8 xcd x 64; 8 bx-panels per XCD
  const int id  = blockIdx.x;
  const int xcd = id & 7, rr = id >> 3;
  const int bx  = xcd * 8 + (rr & 7);
  const int by  = rr >> 3;
  const int row0 = bx * 128;
  const int n0   = by * 128;
  const bool neg = (by >= 4);                // odd-bin group: minus fold
  const int wm = (wave >> 1) * 32;
  const int wn = (wave & 1) * 64;
  const int lr = lane & 15;
  const int kg = (lane >> 4) * 8;

  // ---- fold thread mapping: row = tid>>2 (128), kq = tid&3 (8 folded k each)
  const int arow = tid >> 2;
  const int kq   = tid & 3;
  const float* xlo = x + (size_t)(row0 + arow) * SIG + kq * 8;
  const float* xhi = xlo + 500;
  const float* xsafe = x + (size_t)(row0 + arow) * SIG + 992;  // masked values
  const float* fpa = fp + kq * 8;
  const float* fpb = fp + 512 + kq * 8;

  // ---- B staging: wave w stages 1 KiB chunk w
  const int doffB = wave * 1024;
  const int soffB = doffB + lane * 16;
  const int srowB = soffB >> 6, skbB = (soffB & 63) >> 1;
  const ushort* gB = Bt + (size_t)(n0 + srowB) * FK + skbB;

  auto STAGE_B = [&](int buf, int k0) {
    __builtin_amdgcn_global_load_lds(
        (const __attribute__((address_space(1))) void*)(gB + k0),
        (__attribute__((address_space(3))) void*)((char*)lB[buf] + doffB), 16, 0, 0);
  };
  auto ISSUE_X = [&](float4* d, int t) {
    d[0] = *(const float4*)(xlo + t * 32);
    d[1] = *(const float4*)(xlo + t * 32 + 4);
    if (t == 15) {       // hi quartets that would cross col 999: clamp, fpB masks
      d[2] = *(const float4*)((kq <= 2) ? (xhi + 480) : xsafe);
      d[3] = *(const float4*)((kq <= 1) ? (xhi + 484) : xsafe);
    } else {
      d[2] = *(const float4*)(xhi + t * 32);
      d[3] = *(const float4*)(xhi + t * 32 + 4);
    }
  };
  auto FOLD = [&](const float4* d, int t, int buf) {
    const float4 fa0 = *(const float4*)(fpa + t * 32);
    const float4 fa1 = *(const float4*)(fpa + t * 32 + 4);
    const float4 fb0 = *(const float4*)(fpb + t * 32);
    const float4 fb1 = *(const float4*)(fpb + t * 32 + 4);
    float o[8];
#pragma unroll
    for (int j = 0; j < 4; ++j) {
      float lo0 = d[0][j] * fa0[j], p0 = d[2][j] * fb0[j];
      float lo1 = d[1][j] * fa1[j], p1 = d[3][j] * fb1[j];
      o[j]     = neg ? (lo0 - p0) : (lo0 + p0);
      o[4 + j] = neg ? (lo1 - p1) : (lo1 + p1);
    }
    uint4 v = make_uint4(pk2(o[0], o[1]), pk2(o[2], o[3]),
                         pk2(o[4], o[5]), pk2(o[6], o[7]));
    *(uint4*)&lA[buf][arow * 32 + kq * 8] = v;
  };

  f32x4 acc[2][4] = {};
  float4 xa[4], xb[4];

  // ---- prologue
  fp[tid]       = (tid < 500) ? filt[tid]       : 0.f;
  fp[tid + 512] = (tid < 500) ? filt[tid + 500] : 0.f;
  ISSUE_X(xa, 0); STAGE_B(0, 0);
  SB0();                                   // pin group order for vmcnt ledger
  ISSUE_X(xb, 1); STAGE_B(1, 32);
  SB0(); asm volatile("s_waitcnt lgkmcnt(0)" ::: "memory");
  __builtin_amdgcn_s_barrier(); SB0();     // fp tables visible
  SB0(); asm volatile("s_waitcnt vmcnt(5)" ::: "memory"); SB0();  // x0,B0 done
  FOLD(xa, 0, 0);
  SB0(); asm volatile("s_waitcnt lgkmcnt(0)" ::: "memory");
  __builtin_amdgcn_s_barrier(); SB0();     // lA[0], lB[0] ready

#pragma unroll
  for (int kt = 0; kt < NT; ++kt) {
    const int cur = kt % 3;
    float4* dst = (kt & 1) ? xb : xa;      // set freed by last iter's fold
    const float4* src = (kt & 1) ? xa : xb;  // holds x(kt+1)
    if (kt + 2 < NT) { ISSUE_X(dst, kt + 2); STAGE_B((kt + 2) % 3, (kt + 2) * 32); }
    SB0();
    if (kt <= 13)      asm volatile("s_waitcnt vmcnt(6)" ::: "memory");  // x(kt+1) done
    else if (kt == 14) asm volatile("s_waitcnt vmcnt(1)" ::: "memory");
    SB0();
    if (kt + 1 < NT) FOLD(src, kt + 1, (kt + 1) % 3);   // overlaps MFMA below
    short8 a[2], b[4];
    const ushort* baseA = lA[cur];
    const ushort* baseB = lB[cur];
#pragma unroll
    for (int m = 0; m < 2; ++m)
      a[m] = *(const short8*)&baseA[(wm + m * 16 + lr) * 32 + kg];
#pragma unroll
    for (int n = 0; n < 4; ++n)
      b[n] = *(const short8*)&baseB[(wn + n * 16 + lr) * 32 + kg];
#pragma unroll
    for (int m = 0; m < 2; ++m)
#pragma unroll
      for (int n = 0; n < 4; ++n)
        acc[m][n] = __builtin_amdgcn_mfma_f32_16x16x32_bf16(a[m], b[n], acc[m][n], 0, 0, 0);
    if (kt < NT - 1) {
      SB0();
      if (kt <= 13) asm volatile("s_waitcnt vmcnt(5) lgkmcnt(0)" ::: "memory"); // B(kt+1) done
      else          asm volatile("s_waitcnt vmcnt(0) lgkmcnt(0)" ::: "memory");
      __builtin_amdgcn_s_barrier();
      SB0();
    }
  }

  // epilogue: C/D layout col=lane&15, row=(lane>>4)*4+j (m89/m91 verified)
  const int g = by >> 2;
  const int colpar = lane & 1;
#pragma unroll
  for (int m = 0; m < 2; ++m) {
#pragma unroll
    for (int n = 0; n < 4; ++n) {
#pragma unroll
      for (int j = 0; j < 4; ++j) {
        float v  = acc[m][n][j];
        float v2 = __shfl_xor(v, 1);             // sin partner of the pair
        if (!colpar) {
          int grow = row0 + wm + m * 16 + (lane >> 4) * 4 + j;
          int cg   = ((n0 + wn + n * 16 + lr) & 511);
          int mbin = (cg & ~1) + g;              // 2*pair + group
          psd[(size_t)grow * PSDK + mbin] = f2bf((v * v + v2 * v2) * 1e-6f);
        }
      }
    }
  }
}

// head: out[8192][141] = psd[:, :500] @ W3^T + b3 via bf16 MFMA.
// 16x192 tile, grid 512 (2 blocks/CU), 4 waves (wave 16x48 = 1x3 frags).
// Depth-2 pipeline, rule-#18 pinned boundaries.
__global__ __launch_bounds__(256, 2) void head_gemm_k(
    const ushort* __restrict__ psd, const ushort* __restrict__ W3p,
    const float* __restrict__ b3, float* __restrict__ out) {
  __shared__ ushort lA[3][16 * 32];
  __shared__ ushort lB[3][HN * 32];
  const int tid  = threadIdx.x;
  const int wave = tid >> 6;
  const int lane = tid & 63;
  const int row0 = blockIdx.x * 16;
  const int wn = wave * 48;
  const int lr = lane & 15;
  const int kg = (lane >> 4) * 8;

  const ushort* gs[4];
  int doff[4], isa[4], valid[4];
#pragma unroll
  for (int j = 0; j < 4; ++j) {
    const int i = wave + 4 * j;
    valid[j] = (i < 13);
    const int ia  = (i == 0);
    const int idx = ia ? 0 : (i - 1);
    const int off = (ia ? 0 : idx * 1024) + lane * 16;
    const int row = off >> 6;
    const int kb  = (off & 63) >> 1;
    gs[j]   = ia ? (psd + (size_t)(row0 + row) * PSDK + kb)
                 : (W3p + (size_t)row * PSDK + kb);
    doff[j] = ia ? 0 : idx * 1024;
    isa[j]  = ia;
  }
  auto HSTAGE = [&](int buf, int k0) {
#pragma unroll
    for (int j = 0; j < 4; ++j) {
      if (valid[j]) {
        char* db = (isa[j] ? (char*)lA[buf] : (char*)lB[buf]) + doff[j];
        __builtin_amdgcn_global_load_lds(
            (const __attribute__((address_space(1))) void*)(gs[j] + k0),
            (__attribute__((address_space(3))) void*)db, 16, 0, 0);
      }
    }
  };

  f32x4 acc[3] = {};
  HSTAGE(0, 0);
  HSTAGE(1, 32);
  SB0();
  if (wave == 0) asm volatile("s_waitcnt vmcnt(4)" ::: "memory");
  else           asm volatile("s_waitcnt vmcnt(3)" ::: "memory");
  __builtin_amdgcn_s_barrier();
  SB0();

#pragma unroll
  for (int kt = 0; kt < NT; ++kt) {
    const int cur = kt % 3;
    if (kt + 2 < NT) HSTAGE((kt + 2) % 3, (kt + 2) * 32);
    short8 a, b[3];
    const ushort* baseA = lA[cur];
    const ushort* baseB = lB[cur];
    a = *(const short8*)&baseA[lr * 32 + kg];
#pragma unroll
    for (int n = 0; n < 3; ++n)
      b[n] = *(const short8*)&baseB[(wn + n * 16 + lr) * 32 + kg];
#pragma unroll
    for (int n = 0; n < 3; ++n)
      acc[n] = __builtin_amdgcn_mfma_f32_16x16x32_bf16(a, b[n], acc[n], 0, 0, 0);
    if (kt < NT - 1) {
      SB0();
      if (kt + 2 < NT) {
        if (wave == 0) asm volatile("s_waitcnt vmcnt(4) lgkmcnt(0)" ::: "memory");
        else           asm volatile("s_waitcnt vmcnt(3) lgkmcnt(0)" ::: "memory");
      } else {
        asm volatile("s_waitcnt vmcnt(0) lgkmcnt(0)" ::: "memory");
      }
      __builtin_amdgcn_s_barrier();
      SB0();
    }
  }

#pragma unroll
  for (int n = 0; n < 3; ++n) {
#pragma unroll
    for (int j = 0; j < 4; ++j) {
      int gcol = wn + n * 16 + lr;
      if (gcol < NOUT) {
        int grow = row0 + (lane >> 4) * 4 + j;
        out[(size_t)grow * NOUT + gcol] = acc[n][j] + b3[gcol];
      }
    }
  }
}

extern "C" void kernel_launch(void* const* d_in, const int* in_sizes, int n_in,
                              void* d_out, int out_size, void* d_ws, size_t ws_size,
                              hipStream_t stream) {
  const float* x    = (const float*)d_in[0];
  const float* filt = (const float*)d_in[1];
  // d_in[2] (Wf), d_in[3] (Wfc) unused: DFT weights synthesized on device;
  // r2 = r1, i2 = -i1 algebraically so Wfc's GEMM is redundant.
  const float* W3   = (const float*)d_in[4];
  const float* b3   = (const float*)d_in[5];
  float* out = (float*)d_out;

  char* ws = (char*)d_ws;
  ushort* Bt  = (ushort*)ws;                                     // 1 MiB
  ushort* psd = (ushort*)(ws + (size_t)NPAD * FK * 2);           // +8 MiB
  ushort* W3p = (ushort*)(ws + (size_t)NPAD * FK * 2
                             + (size_t)MROWS * PSDK * 2);        // +192 KiB

  wprep_k<<<(NPAD + HN) / 2, 256, 0, stream>>>(W3, Bt, W3p);
  gemm_psd_k<<<(MROWS / 128) * (NPAD / 128), 512, 0, stream>>>(x, filt, Bt, psd);
  head_gemm_k<<<MROWS / 16, 256, 0, stream>>>(psd, W3p, b3, out);
}

// Round 12
// 46.889 us; speedup vs baseline: 1.0007x; 1.0007x over previous
//
#include <hip/hip_runtime.h>
#include <hip/hip_bf16.h>

#define SIG   1000
#define MROWS 8192
#define FK    512    // folded K (500 used, padded)
#define NPAD  1024   // GEMM N: group0 = even-bin (cos,sin) pairs, group1 = odd-bin
#define PSDK  512    // psd padded columns (500 used) -> head GEMM K
#define HN    192    // head GEMM padded N (141 used)
#define NOUT  141
#define NT    16     // K-tiles (512/32)

using f32x4  = __attribute__((ext_vector_type(4))) float;
using short8 = __attribute__((ext_vector_type(8))) short;

__device__ inline ushort f2bf(float f) {
  union { float f; unsigned u; } v; v.f = f;
  unsigned u = v.u;
  return (ushort)((u + 0x7FFFu + ((u >> 16) & 1u)) >> 16);   // RNE
}
__device__ inline uint pk2(float a, float b) {
  return (uint)f2bf(a) | ((uint)f2bf(b) << 16);
}
#define SB0() __builtin_amdgcn_sched_barrier(0)

// weights-only prep: rows [0,1024) -> Bt (on-device trig), [1024,1216) -> W3p
__global__ __launch_bounds__(256) void wprep_k(
    const float* __restrict__ W3, ushort* __restrict__ Bt,
    ushort* __restrict__ W3p) {
  const int row = blockIdx.x * 2 + (threadIdx.x >> 7);
  const int c   = threadIdx.x & 127;             // ushort4 chunk: k = 4c..4c+3
  if (row < NPAD) {
    const int cg = row & 511, g = row >> 9;
    ushort4 o = make_ushort4(0, 0, 0, 0);
    if (cg < 500) {
      const int m = 2 * (cg >> 1) + g;
      const int trig = cg & 1;
      const float C = 6.28318530717958647692f / 1000.0f;
      ushort v[4];
#pragma unroll
      for (int j = 0; j < 4; ++j) {
        int ph = ((4 * c + j) * m) % 1000;
        float ang = ph * C;
        v[j] = f2bf(trig ? __sinf(ang) : __cosf(ang));
      }
      o = make_ushort4(v[0], v[1], v[2], v[3]);
    }
    ((ushort4*)(Bt + (size_t)row * FK))[c] = o;
  } else {
    const int n = row - NPAD;
    ushort4 o = make_ushort4(0, 0, 0, 0);
    if (n < NOUT && c < 125) {
      const float4 w = *(const float4*)(W3 + (size_t)n * 500 + 4 * c);
      o.x = f2bf(w.x); o.y = f2bf(w.y); o.z = f2bf(w.z); o.w = f2bf(w.w);
    }
    ((ushort4*)(W3p + (size_t)n * PSDK))[c] = o;
  }
}

// Fused fold + DFT GEMM + psd epilogue. A built on the fly from x:
// fh[r][k] = x[r][k]*filt[k] +/- x[r][k+500]*filt[k+500]  (sign by group).
// 128x128 tile, 512 thr / 8 waves (4x2 of 32x64), grid 512 (2 blk/CU).
// 3 LDS buffers; x staged in NAMED float4 regs (rule #20: no arrays, no
// pointer select) 1 iter ahead, fold overlaps MFMA; B via global_load_lds
// 2 ahead. vmcnt ledger: prologue 5; top 6 (tail 1); bottom 5 (tail 0).
__global__ __launch_bounds__(512, 4) void gemm_psd_k(
    const float* __restrict__ x, const float* __restrict__ filt,
    const ushort* __restrict__ Bt, ushort* __restrict__ psd) {
  __shared__ ushort lA[3][128 * 32];   // 3 x 8 KiB
  __shared__ ushort lB[3][128 * 32];   // 3 x 8 KiB
  __shared__ float  fp[1024];          // fpA[0..511]=filt[k]|0, fpB=filt[k+500]|0
  const int tid  = threadIdx.x;
  const int wave = tid >> 6;
  const int lane = tid & 63;
  // bijective XCD swizzle: grid 512 = 8 xcd x 64; 8 bx-panels per XCD
  const int id  = blockIdx.x;
  const int xcd = id & 7, rr = id >> 3;
  const int bx  = xcd * 8 + (rr & 7);
  const int by  = rr >> 3;
  const int row0 = bx * 128;
  const int n0   = by * 128;
  const bool neg = (by >= 4);                // odd-bin group: minus fold
  const int wm = (wave >> 1) * 32;
  const int wn = (wave & 1) * 64;
  const int lr = lane & 15;
  const int kg = (lane >> 4) * 8;

  // fold thread mapping: row = tid>>2 (128 rows), kq = tid&3 (8 folded k each)
  const int arow = tid >> 2;
  const int kq   = tid & 3;
  const float* xlo = x + (size_t)(row0 + arow) * SIG + kq * 8;
  const float* xhi = xlo + 500;
  const float* fpa = fp + kq * 8;
  const float* fpb = fp + 512 + kq * 8;

  // B staging: wave w stages 1 KiB chunk w
  const int doffB = wave * 1024;
  const int soffB = doffB + lane * 16;
  const int srowB = soffB >> 6, skbB = (soffB & 63) >> 1;
  const ushort* gB = Bt + (size_t)(n0 + srowB) * FK + skbB;

#define STAGE_B(buf, k0)                                                        \
  __builtin_amdgcn_global_load_lds(                                             \
      (const __attribute__((address_space(1))) void*)(gB + (k0)),               \
      (__attribute__((address_space(3))) void*)((char*)lB[buf] + doffB), 16, 0, 0)

// t==15's hi quartets past col 999 are clamped to xlo (in-bounds); the zero
// entries of fpb mask them out of the fold.
#define ISSUE_X(d0, d1, d2, d3, t)                                              \
  do {                                                                          \
    d0 = *(const float4*)(xlo + (t) * 32);                                      \
    d1 = *(const float4*)(xlo + (t) * 32 + 4);                                  \
    if ((t) == 15) {                                                            \
      d2 = *(const float4*)((kq <= 2) ? (xhi + 480) : xlo);                     \
      d3 = *(const float4*)((kq <= 1) ? (xhi + 484) : xlo);                     \
    } else {                                                                    \
      d2 = *(const float4*)(xhi + (t) * 32);                                    \
      d3 = *(const float4*)(xhi + (t) * 32 + 4);                                \
    }                                                                           \
  } while (0)

#define FOLD(s0, s1, s2, s3, t, buf)                                            \
  do {                                                                          \
    const float4 fa0 = *(const float4*)(fpa + (t) * 32);                        \
    const float4 fa1 = *(const float4*)(fpa + (t) * 32 + 4);                    \
    const float4 fb0 = *(const float4*)(fpb + (t) * 32);                        \
    const float4 fb1 = *(const float4*)(fpb + (t) * 32 + 4);                    \
    float o0[4], o1[4];                                                         \
    _Pragma("unroll")                                                           \
    for (int j = 0; j < 4; ++j) {                                               \
      float lo0 = s0[j] * fa0[j], p0 = s2[j] * fb0[j];                          \
      float lo1 = s1[j] * fa1[j], p1 = s3[j] * fb1[j];                          \
      o0[j] = neg ? (lo0 - p0) : (lo0 + p0);                                    \
      o1[j] = neg ? (lo1 - p1) : (lo1 + p1);                                    \
    }                                                                           \
    uint4 v = make_uint4(pk2(o0[0], o0[1]), pk2(o0[2], o0[3]),                  \
                         pk2(o1[0], o1[1]), pk2(o1[2], o1[3]));                 \
    *(uint4*)&lA[buf][arow * 32 + kq * 8] = v;                                  \
  } while (0)

  f32x4 acc[2][4] = {};
  float4 xa0, xa1, xa2, xa3, xb0, xb1, xb2, xb3;

  // ---- prologue
  fp[tid]       = (tid < 500) ? filt[tid]       : 0.f;
  fp[tid + 512] = (tid < 500) ? filt[tid + 500] : 0.f;
  ISSUE_X(xa0, xa1, xa2, xa3, 0);
  SB0();
  STAGE_B(0, 0);
  SB0();                                   // pin issue order for vmcnt ledger
  ISSUE_X(xb0, xb1, xb2, xb3, 1);
  SB0();
  STAGE_B(1, 32);
  SB0(); asm volatile("s_waitcnt lgkmcnt(0)" ::: "memory");
  __builtin_amdgcn_s_barrier(); SB0();     // fp tables visible
  SB0(); asm volatile("s_waitcnt vmcnt(5)" ::: "memory"); SB0();  // x0,B0 done
  FOLD(xa0, xa1, xa2, xa3, 0, 0);
  SB0(); asm volatile("s_waitcnt lgkmcnt(0)" ::: "memory");
  __builtin_amdgcn_s_barrier(); SB0();     // lA[0], lB[0] ready

#pragma unroll
  for (int kt = 0; kt < NT; ++kt) {
    const int cur = kt % 3;
    // issue x(kt+2) into the set freed by last iter's fold; x older than B
    if (kt + 2 < NT) {
      if (kt & 1) ISSUE_X(xb0, xb1, xb2, xb3, kt + 2);
      else        ISSUE_X(xa0, xa1, xa2, xa3, kt + 2);
      SB0();
      STAGE_B((kt + 2) % 3, (kt + 2) * 32);
    }
    SB0();
    if (kt <= 13)      asm volatile("s_waitcnt vmcnt(6)" ::: "memory");  // x(kt+1) done
    else if (kt == 14) asm volatile("s_waitcnt vmcnt(1)" ::: "memory");
    SB0();
    if (kt + 1 < NT) {                     // fold x(kt+1) -> lA[(kt+1)%3]; overlaps MFMA
      if (kt & 1) FOLD(xa0, xa1, xa2, xa3, kt + 1, (kt + 1) % 3);
      else        FOLD(xb0, xb1, xb2, xb3, kt + 1, (kt + 1) % 3);
    }
    short8 a[2], b[4];
    const ushort* baseA = lA[cur];
    const ushort* baseB = lB[cur];
#pragma unroll
    for (int m = 0; m < 2; ++m)
      a[m] = *(const short8*)&baseA[(wm + m * 16 + lr) * 32 + kg];
#pragma unroll
    for (int n = 0; n < 4; ++n)
      b[n] = *(const short8*)&baseB[(wn + n * 16 + lr) * 32 + kg];
#pragma unroll
    for (int m = 0; m < 2; ++m)
#pragma unroll
      for (int n = 0; n < 4; ++n)
        acc[m][n] = __builtin_amdgcn_mfma_f32_16x16x32_bf16(a[m], b[n], acc[m][n], 0, 0, 0);
    if (kt < NT - 1) {
      SB0();
      if (kt <= 13) asm volatile("s_waitcnt vmcnt(5) lgkmcnt(0)" ::: "memory"); // B(kt+1) done
      else          asm volatile("s_waitcnt vmcnt(0) lgkmcnt(0)" ::: "memory");
      __builtin_amdgcn_s_barrier();
      SB0();
    }
  }

  // epilogue: C/D layout col=lane&15, row=(lane>>4)*4+j (m89/m91 verified)
  const int g = by >> 2;
  const int colpar = lane & 1;
#pragma unroll
  for (int m = 0; m < 2; ++m) {
#pragma unroll
    for (int n = 0; n < 4; ++n) {
#pragma unroll
      for (int j = 0; j < 4; ++j) {
        float v  = acc[m][n][j];
        float v2 = __shfl_xor(v, 1);             // sin partner of the pair
        if (!colpar) {
          int grow = row0 + wm + m * 16 + (lane >> 4) * 4 + j;
          int cg   = ((n0 + wn + n * 16 + lr) & 511);
          int mbin = (cg & ~1) + g;              // 2*pair + group
          psd[(size_t)grow * PSDK + mbin] = f2bf((v * v + v2 * v2) * 1e-6f);
        }
      }
    }
  }
#undef STAGE_B
#undef ISSUE_X
#undef FOLD
}

// head: out[8192][141] = psd[:, :500] @ W3^T + b3 via bf16 MFMA.
// 16x192 tile, grid 512 (2 blocks/CU), 4 waves (wave 16x48 = 1x3 frags).
// Depth-2 pipeline, rule-#18 pinned boundaries.
__global__ __launch_bounds__(256, 2) void head_gemm_k(
    const ushort* __restrict__ psd, const ushort* __restrict__ W3p,
    const float* __restrict__ b3, float* __restrict__ out) {
  __shared__ ushort lA[3][16 * 32];
  __shared__ ushort lB[3][HN * 32];
  const int tid  = threadIdx.x;
  const int wave = tid >> 6;
  const int lane = tid & 63;
  const int row0 = blockIdx.x * 16;
  const int wn = wave * 48;
  const int lr = lane & 15;
  const int kg = (lane >> 4) * 8;

  const ushort* gs[4];
  int doff[4], isa[4], valid[4];
#pragma unroll
  for (int j = 0; j < 4; ++j) {
    const int i = wave + 4 * j;
    valid[j] = (i < 13);
    const int ia  = (i == 0);
    const int idx = ia ? 0 : (i - 1);
    const int off = (ia ? 0 : idx * 1024) + lane * 16;
    const int row = off >> 6;
    const int kb  = (off & 63) >> 1;
    gs[j]   = ia ? (psd + (size_t)(row0 + row) * PSDK + kb)
                 : (W3p + (size_t)row * PSDK + kb);
    doff[j] = ia ? 0 : idx * 1024;
    isa[j]  = ia;
  }
  auto HSTAGE = [&](int buf, int k0) {
#pragma unroll
    for (int j = 0; j < 4; ++j) {
      if (valid[j]) {
        char* db = (isa[j] ? (char*)lA[buf] : (char*)lB[buf]) + doff[j];
        __builtin_amdgcn_global_load_lds(
            (const __attribute__((address_space(1))) void*)(gs[j] + k0),
            (__attribute__((address_space(3))) void*)db, 16, 0, 0);
      }
    }
  };

  f32x4 acc[3] = {};
  HSTAGE(0, 0);
  HSTAGE(1, 32);
  SB0();
  if (wave == 0) asm volatile("s_waitcnt vmcnt(4)" ::: "memory");
  else           asm volatile("s_waitcnt vmcnt(3)" ::: "memory");
  __builtin_amdgcn_s_barrier();
  SB0();

#pragma unroll
  for (int kt = 0; kt < NT; ++kt) {
    const int cur = kt % 3;
    if (kt + 2 < NT) HSTAGE((kt + 2) % 3, (kt + 2) * 32);
    short8 a, b[3];
    const ushort* baseA = lA[cur];
    const ushort* baseB = lB[cur];
    a = *(const short8*)&baseA[lr * 32 + kg];
#pragma unroll
    for (int n = 0; n < 3; ++n)
      b[n] = *(const short8*)&baseB[(wn + n * 16 + lr) * 32 + kg];
#pragma unroll
    for (int n = 0; n < 3; ++n)
      acc[n] = __builtin_amdgcn_mfma_f32_16x16x32_bf16(a, b[n], acc[n], 0, 0, 0);
    if (kt < NT - 1) {
      SB0();
      if (kt + 2 < NT) {
        if (wave == 0) asm volatile("s_waitcnt vmcnt(4) lgkmcnt(0)" ::: "memory");
        else           asm volatile("s_waitcnt vmcnt(3) lgkmcnt(0)" ::: "memory");
      } else {
        asm volatile("s_waitcnt vmcnt(0) lgkmcnt(0)" ::: "memory");
      }
      __builtin_amdgcn_s_barrier();
      SB0();
    }
  }

#pragma unroll
  for (int n = 0; n < 3; ++n) {
#pragma unroll
    for (int j = 0; j < 4; ++j) {
      int gcol = wn + n * 16 + lr;
      if (gcol < NOUT) {
        int grow = row0 + (lane >> 4) * 4 + j;
        out[(size_t)grow * NOUT + gcol] = acc[n][j] + b3[gcol];
      }
    }
  }
}

extern "C" void kernel_launch(void* const* d_in, const int* in_sizes, int n_in,
                              void* d_out, int out_size, void* d_ws, size_t ws_size,
                              hipStream_t stream) {
  const float* x    = (const float*)d_in[0];
  const float* filt = (const float*)d_in[1];
  // d_in[2] (Wf), d_in[3] (Wfc) unused: DFT weights synthesized on device;
  // r2 = r1, i2 = -i1 algebraically so Wfc's GEMM is redundant.
  const float* W3   = (const float*)d_in[4];
  const float* b3   = (const float*)d_in[5];
  float* out = (float*)d_out;

  char* ws = (char*)d_ws;
  ushort* Bt  = (ushort*)ws;                                     // 1 MiB
  ushort* psd = (ushort*)(ws + (size_t)NPAD * FK * 2);           // +8 MiB
  ushort* W3p = (ushort*)(ws + (size_t)NPAD * FK * 2
                             + (size_t)MROWS * PSDK * 2);        // +192 KiB

  wprep_k<<<(NPAD + HN) / 2, 256, 0, stream>>>(W3, Bt, W3p);
  gemm_psd_k<<<(MROWS / 128) * (NPAD / 128), 512, 0, stream>>>(x, filt, Bt, psd);
  head_gemm_k<<<MROWS / 16, 256, 0, stream>>>(psd, W3p, b3, out);
}

// Round 13
// 36.460 us; speedup vs baseline: 1.2869x; 1.2861x over previous
//
#include <hip/hip_runtime.h>
#include <hip/hip_bf16.h>

#define SIG   1000
#define MROWS 8192
#define FK    512    // folded K (500 used, padded)
#define FW    1024   // fold buffer width: [ce(512) | ho(512)]
#define NPAD  1024   // GEMM N: group0 = even-bin (cos,sin) pairs, group1 = odd-bin
#define PSDK  512    // psd padded columns (500 used) -> head GEMM K
#define HN    192    // head GEMM padded N (141 used)
#define NOUT  141
#define NT    16     // K-tiles per GEMM (512/32)

using f32x4  = __attribute__((ext_vector_type(4))) float;
using short8 = __attribute__((ext_vector_type(8))) short;

__device__ inline ushort f2bf(float f) {
  union { float f; unsigned u; } v; v.f = f;
  unsigned u = v.u;
  unsigned r = (u + 0x7FFFu + ((u >> 16) & 1u)) >> 16;   // RNE
  return (ushort)r;
}

// Rule-#18 hardened pipeline boundary: nothing (MFMA, ds_read, global_load_lds)
// may be scheduled across the waitcnt+barrier pair in either direction.
#define SYNC_BOUNDARY(WAITSTR)                         \
  do {                                                 \
    __builtin_amdgcn_sched_barrier(0);                 \
    asm volatile(WAITSTR ::: "memory");                \
    __builtin_amdgcn_s_barrier();                      \
    __builtin_amdgcn_sched_barrier(0);                 \
  } while (0)

// Merged prep: blocks [0,4096) do the radix-2 fold (2 rows each);
// blocks [4096, 4096+608) build Bt / W3p (2 weight-rows each).
__global__ __launch_bounds__(256) void prep_k(
    const float* __restrict__ x, const float* __restrict__ filt,
    const float* __restrict__ W3, ushort* __restrict__ fh,
    ushort* __restrict__ Bt, ushort* __restrict__ W3p) {
  const int tid = threadIdx.x;
  const int blk = blockIdx.x;
  if (blk < MROWS / 2) {
    // ---- fold: h[k]=x*filt; fh[r][k]=h[k]+h[k+500], fh[r][512+k]=h[k]-h[k+500]
    const int r = blk * 2 + (tid >> 7);
    const int c = tid & 127;               // float4 chunk within 512-col half
    ushort4 e = make_ushort4(0, 0, 0, 0);
    ushort4 o = make_ushort4(0, 0, 0, 0);
    if (c < 125) {
      const float4* xr = (const float4*)(x + (size_t)r * SIG);
      const float4* fr = (const float4*)filt;
      const float4 xl = xr[c],       fl = fr[c];
      const float4 xh = xr[c + 125], fv = fr[c + 125];
      float lx = xl.x * fl.x, ly = xl.y * fl.y, lz = xl.z * fl.z, lw = xl.w * fl.w;
      float hx = xh.x * fv.x, hy = xh.y * fv.y, hz = xh.z * fv.z, hw = xh.w * fv.w;
      e.x = f2bf(lx + hx); e.y = f2bf(ly + hy); e.z = f2bf(lz + hz); e.w = f2bf(lw + hw);
      o.x = f2bf(lx - hx); o.y = f2bf(ly - hy); o.z = f2bf(lz - hz); o.w = f2bf(lw - hw);
    }
    ((ushort4*)(fh + (size_t)r * FW))[c]      = e;
    ((ushort4*)(fh + (size_t)r * FW + FK))[c] = o;
  } else {
    // ---- weight build: rows [0,1024) -> Bt, [1024,1216) -> W3p
    const int row = (blk - MROWS / 2) * 2 + (tid >> 7);
    const int c   = tid & 127;             // ushort4 chunk: k = 4c..4c+3
    if (row < NPAD) {
      const int cg = row & 511, g = row >> 9;
      ushort4 o = make_ushort4(0, 0, 0, 0);
      if (cg < 500) {
        const int m = 2 * (cg >> 1) + g;
        const int trig = cg & 1;
        const float C = 6.28318530717958647692f / 1000.0f;
        ushort v[4];
#pragma unroll
        for (int j = 0; j < 4; ++j) {
          int ph = ((4 * c + j) * m) % 1000;
          float ang = ph * C;
          v[j] = f2bf(trig ? __sinf(ang) : __cosf(ang));
        }
        o = make_ushort4(v[0], v[1], v[2], v[3]);
      }
      ((ushort4*)(Bt + (size_t)row * FK))[c] = o;
    } else {
      const int n = row - NPAD;
      ushort4 o = make_ushort4(0, 0, 0, 0);
      if (n < NOUT && c < 125) {           // 4c+3 <= 499
        const float4 w = *(const float4*)(W3 + (size_t)n * 500 + 4 * c);
        o.x = f2bf(w.x); o.y = f2bf(w.y); o.z = f2bf(w.z); o.w = f2bf(w.w);
      }
      ((ushort4*)(W3p + (size_t)n * PSDK))[c] = o;
    }
  }
}

// Folded DFT GEMM + psd epilogue. M=8192, K=512, N=1024.
// 128x128 tile, 512 threads / 8 waves (4x2, wave 32x64 = 2x4 frags),
// grid 512 (2 blocks/CU, 16 waves/CU) — R8's proven config.
// NEW: k-slot XOR swizzle (rule #21 with global_load_lds: linear LDS dest +
// inverse-swizzled global SOURCE quarter + swizzled frag read). LDS row r
// slot s holds global k-quarter (s ^ (r&3)) -> b128 frag reads go 8-way ->
// 4-way bank conflict. Depth-2 pipeline: 3 LDS buffers, counted
// s_waitcnt vmcnt(2) across s_barrier, rule-#18 pinned boundaries.
__global__ __launch_bounds__(512, 4) void gemm_psd_k(
    const ushort* __restrict__ A, const ushort* __restrict__ Bt,
    ushort* __restrict__ psd) {
  __shared__ ushort lA[3][128 * 32];   // 3 x 8 KiB
  __shared__ ushort lB[3][128 * 32];   // 3 x 8 KiB
  const int tid  = threadIdx.x;
  const int wave = tid >> 6;
  const int lane = tid & 63;
  // bijective XCD swizzle: grid 512 = 8 xcd x 64; 8 bx-panels per XCD
  const int id  = blockIdx.x;
  const int xcd = id & 7, rr = id >> 3;
  const int bx  = xcd * 8 + (rr & 7);        // [0,64)
  const int by  = rr >> 3;                   // [0,8)
  const int row0 = bx * 128;
  const int n0   = by * 128;
  const int aoff = (by >= 4) ? FK : 0;       // ce vs ho half
  const int wm = (wave >> 1) * 32;           // 4 row-groups
  const int wn = (wave & 1) * 64;            // 2 col-groups
  const int lr = lane & 15;
  // swizzled frag-read slot: quarter (lane>>4) of row with row&3 == lane&3
  // lives at slot (lane>>4) ^ (lane&3)
  const int kgs = (((lane >> 4) ^ (lane & 3)) & 3) * 8;

  // staging: A = 8 chunks of 1 KiB, B = 8 chunks; wave w stages A-chunk w,
  // B-chunk w. LDS dest is linear (lane*16); the SOURCE quarter is
  // inverse-swizzled so LDS row r slot s = global quarter (s ^ (r&3)).
  const int doff = wave * 1024;
  const int srow = wave * 16 + (lane >> 2);              // LDS row this lane fills
  const int skb  = (((lane & 3) ^ ((lane >> 2) & 3)) & 3) * 8;  // source quarter
  const ushort* gA = A  + (size_t)(row0 + srow) * FW + aoff + skb;
  const ushort* gB = Bt + (size_t)(n0   + srow) * FK + skb;

  auto STAGE = [&](int buf, int k0) {
    __builtin_amdgcn_global_load_lds(
        (const __attribute__((address_space(1))) void*)(gA + k0),
        (__attribute__((address_space(3))) void*)((char*)lA[buf] + doff), 16, 0, 0);
    __builtin_amdgcn_global_load_lds(
        (const __attribute__((address_space(1))) void*)(gB + k0),
        (__attribute__((address_space(3))) void*)((char*)lB[buf] + doff), 16, 0, 0);
  };

  f32x4 acc[2][4] = {};

  STAGE(0, 0);
  STAGE(1, 32);
  SYNC_BOUNDARY("s_waitcnt vmcnt(2)");   // buf0 ready, buf1's 2 loads in flight

#pragma unroll
  for (int kt = 0; kt < NT; ++kt) {
    const int cur = kt % 3;
    if (kt + 2 < NT) STAGE((kt + 2) % 3, (kt + 2) * 32);
    short8 a[2], b[4];
    const ushort* baseA = lA[cur];
    const ushort* baseB = lB[cur];
#pragma unroll
    for (int m = 0; m < 2; ++m)
      a[m] = *(const short8*)&baseA[(wm + m * 16 + lr) * 32 + kgs];
#pragma unroll
    for (int n = 0; n < 4; ++n)
      b[n] = *(const short8*)&baseB[(wn + n * 16 + lr) * 32 + kgs];
#pragma unroll
    for (int m = 0; m < 2; ++m)
#pragma unroll
      for (int n = 0; n < 4; ++n)
        acc[m][n] = __builtin_amdgcn_mfma_f32_16x16x32_bf16(a[m], b[n], acc[m][n], 0, 0, 0);
    if (kt < NT - 1) {
      if (kt + 2 < NT)
        SYNC_BOUNDARY("s_waitcnt vmcnt(2) lgkmcnt(0)");  // next buf ready, newest in flight
      else
        SYNC_BOUNDARY("s_waitcnt vmcnt(0) lgkmcnt(0)");  // tail drain
    }
  }

  // epilogue: C/D layout col=lane&15, row=(lane>>4)*4+j (m89/m91 verified)
  const int g = by >> 2;
  const int colpar = lane & 1;
#pragma unroll
  for (int m = 0; m < 2; ++m) {
#pragma unroll
    for (int n = 0; n < 4; ++n) {
#pragma unroll
      for (int j = 0; j < 4; ++j) {
        float v  = acc[m][n][j];
        float v2 = __shfl_xor(v, 1);             // sin partner of the pair
        if (!colpar) {
          int grow = row0 + wm + m * 16 + (lane >> 4) * 4 + j;
          int cg   = ((n0 + wn + n * 16 + lr) & 511);
          int mbin = (cg & ~1) + g;              // 2*pair + group
          psd[(size_t)grow * PSDK + mbin] = f2bf((v * v + v2 * v2) * 1e-6f);
        }
      }
    }
  }
}

// head: out[8192][141] = psd[:, :500] @ W3^T + b3 via bf16 MFMA.
// 16x192 tile, grid 512 (2 blocks/CU), 4 waves (wave 16x48 = 1x3 frags).
// Depth-2 pipeline, rule-#18 pinned boundaries. (Unchanged from R8.)
__global__ __launch_bounds__(256, 2) void head_gemm_k(
    const ushort* __restrict__ psd, const ushort* __restrict__ W3p,
    const float* __restrict__ b3, float* __restrict__ out) {
  __shared__ ushort lA[3][16 * 32];    // 3 x 1 KiB
  __shared__ ushort lB[3][HN * 32];    // 3 x 12 KiB
  const int tid  = threadIdx.x;
  const int wave = tid >> 6;
  const int lane = tid & 63;
  const int row0 = blockIdx.x * 16;
  const int wn = wave * 48;
  const int lr = lane & 15;
  const int kg = (lane >> 4) * 8;

  // staging: 13 chunks (A:1, B:12); wave w -> chunks {w, w+4, w+8, w+12} (<13)
  const ushort* gs[4];
  int doff[4], isa[4], valid[4];
#pragma unroll
  for (int j = 0; j < 4; ++j) {
    const int i = wave + 4 * j;
    valid[j] = (i < 13);
    const int ia  = (i == 0);
    const int idx = ia ? 0 : (i - 1);
    const int off = (ia ? 0 : idx * 1024) + lane * 16;
    const int row = off >> 6;
    const int kb  = (off & 63) >> 1;
    gs[j]   = ia ? (psd + (size_t)(row0 + row) * PSDK + kb)
                 : (W3p + (size_t)row * PSDK + kb);
    doff[j] = ia ? 0 : idx * 1024;
    isa[j]  = ia;
  }

  auto HSTAGE = [&](int buf, int k0) {
#pragma unroll
    for (int j = 0; j < 4; ++j) {
      if (valid[j]) {
        char* db = (isa[j] ? (char*)lA[buf] : (char*)lB[buf]) + doff[j];
        __builtin_amdgcn_global_load_lds(
            (const __attribute__((address_space(1))) void*)(gs[j] + k0),
            (__attribute__((address_space(3))) void*)db, 16, 0, 0);
      }
    }
  };

  f32x4 acc[3] = {};

  HSTAGE(0, 0);
  HSTAGE(1, 32);
  // wave 0 stages 4 chunks/buffer, waves 1-3 stage 3 (wave-uniform branch)
  __builtin_amdgcn_sched_barrier(0);
  if (wave == 0) asm volatile("s_waitcnt vmcnt(4)" ::: "memory");
  else           asm volatile("s_waitcnt vmcnt(3)" ::: "memory");
  __builtin_amdgcn_s_barrier();
  __builtin_amdgcn_sched_barrier(0);

#pragma unroll
  for (int kt = 0; kt < NT; ++kt) {
    const int cur = kt % 3;
    if (kt + 2 < NT) HSTAGE((kt + 2) % 3, (kt + 2) * 32);
    short8 a, b[3];
    const ushort* baseA = lA[cur];
    const ushort* baseB = lB[cur];
    a = *(const short8*)&baseA[lr * 32 + kg];
#pragma unroll
    for (int n = 0; n < 3; ++n)
      b[n] = *(const short8*)&baseB[(wn + n * 16 + lr) * 32 + kg];
#pragma unroll
    for (int n = 0; n < 3; ++n)
      acc[n] = __builtin_amdgcn_mfma_f32_16x16x32_bf16(a, b[n], acc[n], 0, 0, 0);
    if (kt < NT - 1) {
      __builtin_amdgcn_sched_barrier(0);
      if (kt + 2 < NT) {
        if (wave == 0) asm volatile("s_waitcnt vmcnt(4) lgkmcnt(0)" ::: "memory");
        else           asm volatile("s_waitcnt vmcnt(3) lgkmcnt(0)" ::: "memory");
      } else {
        asm volatile("s_waitcnt vmcnt(0) lgkmcnt(0)" ::: "memory");
      }
      __builtin_amdgcn_s_barrier();
      __builtin_amdgcn_sched_barrier(0);
    }
  }

#pragma unroll
  for (int n = 0; n < 3; ++n) {
#pragma unroll
    for (int j = 0; j < 4; ++j) {
      int gcol = wn + n * 16 + lr;
      if (gcol < NOUT) {
        int grow = row0 + (lane >> 4) * 4 + j;
        out[(size_t)grow * NOUT + gcol] = acc[n][j] + b3[gcol];
      }
    }
  }
}

extern "C" void kernel_launch(void* const* d_in, const int* in_sizes, int n_in,
                              void* d_out, int out_size, void* d_ws, size_t ws_size,
                              hipStream_t stream) {
  const float* x    = (const float*)d_in[0];
  const float* filt = (const float*)d_in[1];
  // d_in[2] (Wf), d_in[3] (Wfc) unused: DFT weights synthesized on device;
  // r2 = r1, i2 = -i1 algebraically so Wfc's GEMM is redundant.
  const float* W3   = (const float*)d_in[4];
  const float* b3   = (const float*)d_in[5];
  float* out = (float*)d_out;

  char* ws = (char*)d_ws;
  ushort* fh  = (ushort*)ws;                                     // 16 MiB
  ushort* Bt  = (ushort*)(ws + (size_t)MROWS * FW * 2);          // +1 MiB
  ushort* psd = (ushort*)(ws + (size_t)MROWS * FW * 2
                             + (size_t)NPAD * FK * 2);           // +8 MiB
  ushort* W3p = (ushort*)(ws + (size_t)MROWS * FW * 2
                             + (size_t)NPAD * FK * 2
                             + (size_t)MROWS * PSDK * 2);        // +192 KiB

  prep_k<<<MROWS / 2 + (NPAD + HN) / 2, 256, 0, stream>>>(x, filt, W3, fh, Bt, W3p);
  gemm_psd_k<<<(MROWS / 128) * (NPAD / 128), 512, 0, stream>>>(fh, Bt, psd);
  head_gemm_k<<<MROWS / 16, 256, 0, stream>>>(psd, W3p, b3, out);
}